// Round 6
// baseline (234.537 us; speedup 1.0000x reference)
//
#include <hip/hip_runtime.h>

// RNN: B=2048 chains, T=1024 steps, H=64, I=1. One wave per chain.
// Round-6 theory: round-5's W tile was parked in AGPRs (VGPR_Count=56 < 64
// W values; +1 v_accvgpr_read per FMA = the 2x instruction inflation).
// Fix: amdgpu_waves_per_eu(2,2) clamps occupancy target to exactly the
// grid's residency (2 waves/SIMD) -> 256-reg budget with no incentive to
// minimize arch VGPRs -> W stays in arch VGPRs.
//  * v_pk_fma_f32 inner loop (32 packed FMA/step).
//  * rotated-row W + 3-op DPP ring reduce-scatter, one tanh/lane.
//  * tanh via v_exp_f32 directly: exp(2t) = exp2(t * 2*log2(e)).
//  * single wave/block -> DS in-order, no barriers.

constexpr int T_STEPS = 1024;
constexpr int H = 64;

typedef float v2f __attribute__((ext_vector_type(2)));
typedef float v4f __attribute__((ext_vector_type(4)));

__device__ __forceinline__ float dpp_rotfwd_add(float t, float a) {
    // within each quad: lane q receives t from lane (q+1)&3, then adds a.
    int y = __builtin_amdgcn_mov_dpp(__builtin_bit_cast(int, t), 0x39, 0xF, 0xF, true);
    return __builtin_bit_cast(float, y) + a;
}

__device__ __forceinline__ float tanh_fast(float s) {
    // tanh(s) = 1 - 2/(exp2(s*2log2e)+1); saturates correctly at +-1.
    const float e = __builtin_amdgcn_exp2f(s * 2.88539008177792681472f);
    return 1.f - 2.f * __builtin_amdgcn_rcpf(e + 1.f);
}

__global__
__attribute__((amdgpu_flat_work_group_size(64, 64), amdgpu_waves_per_eu(2, 2)))
void rnn_fused(
    const float* __restrict__ x,      // [B, T, 1]
    const float* __restrict__ W_ih,   // [H, 1]
    const float* __restrict__ W_hh,   // [H, H] row-major
    const float* __restrict__ b_ih,   // [H]
    const float* __restrict__ b_hh,   // [H]
    const float* __restrict__ W_out,  // [1, H]
    const float* __restrict__ b_out,  // [1]
    float* __restrict__ out)          // [B, 1]
{
    const int b    = blockIdx.x;
    const int lane = threadIdx.x;     // 0..63
    const int og   = lane >> 2;
    const int kg   = lane & 3;        // k-slice [16kg, 16kg+16)

    __shared__ v4f xs4[T_STEPS / 4];  // 4 KiB: x[b, :]
    __shared__ v4f hA4[H / 4];
    __shared__ v4f hB4[H / 4];

    // Stage x[b, :], coalesced float4.
    const v4f* xrow = reinterpret_cast<const v4f*>(x + (size_t)b * T_STEPS);
    #pragma unroll
    for (int k = 0; k < T_STEPS / 4 / 64; ++k)
        xs4[lane + 64 * k] = xrow[lane + 64 * k];

    // W tile as float2 pairs, rotated rows: slot r holds row 4og+((kg+r)&3),
    // cols [16kg,16kg+16) as 8 adjacent pairs.
    v2f w2[4][8];
    #pragma unroll
    for (int r = 0; r < 4; ++r) {
        const int row = 4 * og + ((kg + r) & 3);
        const float* src = W_hh + (size_t)row * H + 16 * kg;
        #pragma unroll
        for (int c2 = 0; c2 < 8; ++c2)
            w2[r][c2] = *reinterpret_cast<const v2f*>(src + 2 * c2);
    }
    // Non-rematerializable barrier; with waves_per_eu(2,2) the allocator
    // has a 256-reg budget and no occupancy reason to park these in AGPRs.
    #pragma unroll
    for (int r = 0; r < 4; ++r)
        #pragma unroll
        for (int c2 = 0; c2 < 8; ++c2)
            asm volatile("" : "+v"(w2[r][c2]));

    // Per-lane scalars for OUR output (index = lane).
    const float wih  = W_ih[lane];
    const float bias = b_ih[lane] + b_hh[lane];
    const float wout = W_out[lane];

    reinterpret_cast<float*>(hA4)[lane] = 0.f;   // h0 = 0

    float hn = 0.f;

    auto step = [&](float xv, const v4f* __restrict__ hr,
                    float* __restrict__ hw) {
        const v4f* h4 = hr + 4 * kg;
        // 8 packed accumulators (dep chains of 4). xp seed for OUR output
        // folded into accL[0].x; a[0] is added at the home lane on the
        // final ring pass so it lands in the right output.
        v2f accL[4], accM[4];
        accL[0] = v2f{fmaf(xv, wih, bias), 0.f};
        accL[1] = v2f{0.f, 0.f}; accL[2] = v2f{0.f, 0.f}; accL[3] = v2f{0.f, 0.f};
        accM[0] = v2f{0.f, 0.f}; accM[1] = v2f{0.f, 0.f};
        accM[2] = v2f{0.f, 0.f}; accM[3] = v2f{0.f, 0.f};
        #pragma unroll
        for (int c = 0; c < 4; ++c) {
            const v4f hv = h4[c];                           // ds_read_b128
            const v2f hlo = __builtin_shufflevector(hv, hv, 0, 1);
            const v2f hhi = __builtin_shufflevector(hv, hv, 2, 3);
            #pragma unroll
            for (int r = 0; r < 4; ++r) {
                accL[r] = __builtin_elementwise_fma(hlo, w2[r][2 * c],     accL[r]);
                accM[r] = __builtin_elementwise_fma(hhi, w2[r][2 * c + 1], accM[r]);
            }
        }
        // Merge packed halves: 4 pk_add + 4 scalar adds.
        float a[4];
        #pragma unroll
        for (int r = 0; r < 4; ++r) {
            const v2f s2 = accL[r] + accM[r];
            a[r] = s2.x + s2.y;
        }
        // Reduce-scatter ring (3 dpp-adds): lane q ends with the complete
        // sum for output 4og+q (incl. xp seed via a[0]).
        float t = a[1];
        t = dpp_rotfwd_add(t, a[2]);
        t = dpp_rotfwd_add(t, a[3]);
        t = dpp_rotfwd_add(t, a[0]);
        hn = tanh_fast(t);
        hw[lane] = hn;                                      // stride-4: free
    };

    #pragma unroll 1
    for (int t4 = 0; t4 < T_STEPS / 4; ++t4) {
        const v4f xq = xs4[t4];                             // uniform b128 read
        step(xq.x, hA4, reinterpret_cast<float*>(hB4));
        step(xq.y, hB4, reinterpret_cast<float*>(hA4));
        step(xq.z, hA4, reinterpret_cast<float*>(hB4));
        step(xq.w, hB4, reinterpret_cast<float*>(hA4));
    }

    // out[b] = sigmoid(sum_i h[i] * W_out[i] + b_out); h[i] lives in lane i.
    float p = hn * wout;
    #pragma unroll
    for (int off = 1; off <= 32; off <<= 1)
        p += __shfl_xor(p, off);
    if (lane == 0)
        out[b] = 1.f / (1.f + __expf(-(p + b_out[0])));
}

extern "C" void kernel_launch(void* const* d_in, const int* in_sizes, int n_in,
                              void* d_out, int out_size, void* d_ws, size_t ws_size,
                              hipStream_t stream)
{
    const float* x     = (const float*)d_in[0];
    const float* W_ih  = (const float*)d_in[1];
    const float* W_hh  = (const float*)d_in[2];
    const float* b_ih  = (const float*)d_in[3];
    const float* b_hh  = (const float*)d_in[4];
    const float* W_out = (const float*)d_in[5];
    const float* b_out = (const float*)d_in[6];
    float* out = (float*)d_out;

    const int B = out_size;  // one wave per chain
    rnn_fused<<<B, 64, 0, stream>>>(x, W_ih, W_hh, b_ih, b_hh, W_out, b_out, out);
}